// Round 9
// baseline (934.851 us; speedup 1.0000x reference)
//
#include <hip/hip_runtime.h>
#include <hip/hip_bf16.h>

typedef unsigned short ushort_t;
typedef unsigned int uint_t;
typedef unsigned long long u64_t;

#define BB 16
#define TE 128
#define TD 64
#define HH 256
#define G3 768
#define KK 256
#define OUTV 32000
#define MROWS_E (BB*TE)   // 2048
#define MROWS_D (BB*TD)   // 1024
#define NBLK 4            // GRU blocks; each owns JD h-dims
#define JD 64
#define WROWS 192         // 3 gates x 64 dims of Whh rows per block
#define QW_PER_BUF 2048   // {2xbf16, tag} qwords per h snapshot

typedef __attribute__((ext_vector_type(8))) short short8;
typedef __attribute__((ext_vector_type(4))) float f32x4;

__device__ __forceinline__ float b2f(ushort_t u) {
  union { uint_t i; float f; } v; v.i = ((uint_t)u) << 16; return v.f;
}
__device__ __forceinline__ ushort_t f2b(float f) {
  union { float f; uint_t i; } v; v.f = f;
  uint_t x = v.i;
  return (ushort_t)((x + 0x7fffu + ((x >> 16) & 1u)) >> 16);
}
// dtype-adaptive scalar load of a "float" input: f32f!=0 -> fp32 buffer, else bf16
__device__ __forceinline__ float ldf(const void* p, size_t i, uint_t f32f) {
  return f32f ? ((const float*)p)[i] : b2f(((const ushort_t*)p)[i]);
}
// fast, saturating sigmoid/tanh (inputs bounded; formulas robust at +-inf)
__device__ __forceinline__ float fsig(float x) { return 1.f/(1.f + __expf(-x)); }
__device__ __forceinline__ float ftanh(float x) { return 1.f - 2.f/(__expf(2.f*x) + 1.f); }

// ---------------------------------------------------------------------------
// dtype detector (fp32 on this harness; kept for safety).
// ---------------------------------------------------------------------------
__global__ __launch_bounds__(256) void detect_kernel(const void* emb, uint_t* flag) {
  int tid = threadIdx.x;
  uint_t w = ((const uint_t*)emb)[tid];
  uint_t e = (w >> 7) & 0xFFu;
  bool pass = (e >= 100u && e <= 127u);
  unsigned long long m = __ballot(pass);
  __shared__ int cnt[4];
  if ((tid & 63) == 0) cnt[tid >> 6] = __popcll(m);
  __syncthreads();
  if (tid == 0) {
    int c = cnt[0] + cnt[1] + cnt[2] + cnt[3];
    *flag = (c >= 128) ? 0u : 1u;
  }
}

// ---------------------------------------------------------------------------
// prep: Whh -> bf16 [768][256]; dense_W -> bf16 transpose; combined gi biases
// (bih + bhh folded for r,z gates); out bias -> fp32; zero tagged h-exchange
// buffer (tag 0 == initial h state, value 0 -- re-zeroed every replay).
// ---------------------------------------------------------------------------
__global__ __launch_bounds__(256) void prep_kernel(
    const void* eWhh, const void* dWhh, const void* denseW,
    const void* ebih, const void* ebhh, const void* dbih, const void* dbhh,
    const void* outb, const uint_t* flagp,
    ushort_t* WBe, ushort_t* WBd, ushort_t* DWT,
    float* cbe, float* cbd, float* obf, u64_t* hq) {
  uint_t f = *flagp;
  int tid = blockIdx.x * blockDim.x + threadIdx.x;
  int nth = gridDim.x * blockDim.x;
  for (int i = tid; i < G3*KK; i += nth) {
    WBe[i] = f2b(ldf(eWhh, i, f));
    WBd[i] = f2b(ldf(dWhh, i, f));
  }
  for (int i = tid; i < 512*HH; i += nth) {
    int k = i / HH, c = i % HH;
    DWT[i] = f2b(ldf(denseW, (size_t)c*512 + k, f));
  }
  for (int i = tid; i < G3; i += nth) {
    float be = ldf(ebih, i, f), bd = ldf(dbih, i, f);
    if (i < 2*HH) { be += ldf(ebhh, i, f); bd += ldf(dbhh, i, f); }
    cbe[i] = be; cbd[i] = bd;
  }
  for (int i = tid; i < OUTV; i += nth) obf[i] = ldf(outb, i, f);
  for (int i = tid; i < 2*QW_PER_BUF; i += nth) hq[i] = 0ull;  // tag0 + h=0
}

// ---------------------------------------------------------------------------
// Generic MFMA GEMM: C[m][n] = sum_k A[m][k]*B[n][k] (+bias[n]), K=256 fixed.
// tshift!=0: output rows remapped m=(b*T+t) -> t*BB+b with T=1<<tshift.
// a_f32!=0: ws A operand is fp32 (converted to bf16 during staging).
// bias (if non-null) is always fp32 (prep-produced).
// ---------------------------------------------------------------------------
#define LDT 264

__global__ __launch_bounds__(256) void gemm_kernel(
    const ushort_t* A, const int* tokens, const void* emb,
    const void* Bw, int ldb, int b_off,
    const float* bias, const uint_t* flagp,
    float* Cf, ushort_t* Cb, int ldc, int M, int tshift, int a_f32) {
  __shared__ __align__(16) ushort_t Bs[64*LDT];
  __shared__ __align__(16) ushort_t As[32*LDT];
  uint_t f = *flagp;
  int tid = threadIdx.x;
  int wave = tid >> 6, lane = tid & 63;
  int n0 = blockIdx.x * 64;
#pragma unroll
  for (int it = 0; it < 8; ++it) {
    int idx = it*256 + tid;
    int row = idx >> 5, col = (idx & 31) << 3;
    size_t e = (size_t)(n0 + row)*ldb + col + b_off;
    uint4 v;
    if (f) {
      const float4* s = (const float4*)((const float*)Bw + e);
      float4 x = s[0], y = s[1];
      v.x = (uint_t)f2b(x.x) | ((uint_t)f2b(x.y) << 16);
      v.y = (uint_t)f2b(x.z) | ((uint_t)f2b(x.w) << 16);
      v.z = (uint_t)f2b(y.x) | ((uint_t)f2b(y.y) << 16);
      v.w = (uint_t)f2b(y.z) | ((uint_t)f2b(y.w) << 16);
    } else {
      v = *(const uint4*)((const ushort_t*)Bw + e);
    }
    *(uint4*)(Bs + row*LDT + col) = v;
  }
  int arow_i = lane & 15;
  float bias_v = 0.f;
  if (bias) bias_v = bias[n0 + wave*16 + arow_i];
  int koff = (lane >> 4) << 3;
  for (int m0 = blockIdx.y*32; m0 < M; m0 += gridDim.y*32) {
    __syncthreads();   // Bs ready / previous chunk compute done
#pragma unroll
    for (int it = 0; it < 4; ++it) {
      int idx = it*256 + tid;
      int row = idx >> 5, col = (idx & 31) << 3;
      uint4 v;
      if (tokens) {
        size_t e = (size_t)tokens[m0 + row]*KK + col;
        if (f) {
          const float4* s = (const float4*)((const float*)emb + e);
          float4 x = s[0], y = s[1];
          v.x = (uint_t)f2b(x.x) | ((uint_t)f2b(x.y) << 16);
          v.y = (uint_t)f2b(x.z) | ((uint_t)f2b(x.w) << 16);
          v.z = (uint_t)f2b(y.x) | ((uint_t)f2b(y.y) << 16);
          v.w = (uint_t)f2b(y.z) | ((uint_t)f2b(y.w) << 16);
        } else {
          v = *(const uint4*)((const ushort_t*)emb + e);
        }
      } else if (a_f32) {
        const float4* s = (const float4*)((const float*)A + (size_t)(m0 + row)*KK + col);
        float4 x = s[0], y = s[1];
        v.x = (uint_t)f2b(x.x) | ((uint_t)f2b(x.y) << 16);
        v.y = (uint_t)f2b(x.z) | ((uint_t)f2b(x.w) << 16);
        v.z = (uint_t)f2b(y.x) | ((uint_t)f2b(y.y) << 16);
        v.w = (uint_t)f2b(y.z) | ((uint_t)f2b(y.w) << 16);
      } else {
        v = *(const uint4*)(A + (size_t)(m0 + row)*KK + col);  // ws bf16
      }
      *(uint4*)(As + row*LDT + col) = v;
    }
    __syncthreads();
#pragma unroll
    for (int msub = 0; msub < 2; ++msub) {
      f32x4 acc = {0.f,0.f,0.f,0.f};
      const ushort_t* ap = As + (msub*16 + arow_i)*LDT + koff;
      const ushort_t* bp = Bs + (wave*16 + arow_i)*LDT + koff;
#pragma unroll
      for (int ks = 0; ks < 8; ++ks) {
        short8 af = *(const short8*)(ap + ks*32);
        short8 bf = *(const short8*)(bp + ks*32);
        acc = __builtin_amdgcn_mfma_f32_16x16x32_bf16(af, bf, acc, 0, 0, 0);
      }
      int mbase = m0 + msub*16 + (lane >> 4)*4;
      int ncol = n0 + wave*16 + arow_i;
#pragma unroll
      for (int r = 0; r < 4; ++r) {
        float val = acc[r] + bias_v;
        int mr = mbase + r;
        int orow = tshift ? (((mr & ((1 << tshift) - 1)) << 4) + (mr >> tshift)) : mr;
        if (Cf) Cf[(size_t)orow*ldc + ncol] = val;
        else    Cb[(size_t)orow*ldc + ncol] = f2b(val);
      }
    }
  }
}

// ---------------------------------------------------------------------------
// Multi-CU MFMA GRU, round 9: 4 blocks x 64 h-dims (was 16 x 16).
//
// Round-8 counters: active CUs ~88% idle -> step time is exchange latency +
// 16-participant queuing/skew, not compute. With 4 blocks, each block's 192
// Whh gate-rows (101 KB bf16) are still LDS-resident, and the h exchange has
// 4 publishers / 4 poll-regions: 4x less coherent-point queue pressure and
// tighter publisher skew. Wave w's K-slice [64w,64w+64) coincides exactly
// with source block w's published region.
//
// Protocol (tags, double-buffered hq, bounded guard) is IDENTICAL to r6/r8;
// the write-after-read safety argument is participant-count-independent
// (observed tag s in a region implies its owner passed all its step-s polls,
// so it no longer reads the buffer being overwritten). part[] loses its
// parity double-buffer (52 KB flat) -- a second block-local __syncthreads
// per step replaces it. Reduction order (w=0..3, ks=0..1) unchanged ->
// bit-identical arithmetic vs r8.
//
// Layout: qword index for block b's pair p (p in [0,32), dims 2p,2p+1 of its
// 64) and batch m:  qidx = b*512 + (p>>4)*256 + ((p>>2)&3)*64 + (p&3)*16 + m.
// Reader wave w, thread (mrow,quad), load (ks,e) reads
//   hq + buf + w*512 + ks*256 + e*16 + quad*64 + mrow
// giving A-frag pairs k = 64w + ks*32 + quad*8 + 2e (+1) for batch mrow --
// the same proven r6 fragment mapping, re-based.
// ---------------------------------------------------------------------------
#define HSBF 264            // LDS row stride (bf16 elems): <=2-way banks on b128

__device__ __forceinline__ void stage_w(const ushort_t* WB, int j0, int tid,
                                        ushort_t* wlds) {
#pragma unroll
  for (int it = 0; it < 24; ++it) {
    int idx = it*256 + tid;
    int row = idx >> 5, col = (idx & 31) << 3;   // row 0..191, col 0..255 step 8
    const ushort_t* src = WB + ((size_t)((row >> 6)*HH + j0 + (row & 63)))*KK + col;
    *(uint4*)(wlds + row*HSBF + col) = *(const uint4*)src;
  }
}

__global__ __launch_bounds__(256) void gru_kernel(
    const float* gi_e, const float* gi_d, const ushort_t* WBe, const ushort_t* WBd,
    const void* ebhh, const void* dbhh, const uint_t* flagp,
    const int* elen, const int* dlen, float* eout, float* dout, u64_t* hq) {
  uint_t f = *flagp;
  __shared__ __align__(16) ushort_t wlds[WROWS*HSBF];     // 101376 B
  __shared__ __align__(16) float part[4][12][16][17];     // 52224 B
  const int tid = threadIdx.x;
  const int wave = tid >> 6, lane = tid & 63;
  const int mrow = lane & 15, quad = lane >> 4;           // MFMA fragment coords
  const int bid = blockIdx.x;
  const int j0 = bid * JD;
  const int m = tid >> 4, g = tid & 15;                   // EW: batch m, dim group g
  const int jb = 4*g;                                     // local dim base
  // publish qword indices for local pairs 2g and 2g+1:
  const int pl0 = 2*g, pl1 = 2*g + 1;
  const int widx0 = bid*512 + (pl0 >> 4)*256 + ((pl0 >> 2) & 3)*64 + (pl0 & 3)*16 + m;
  const int widx1 = bid*512 + (pl1 >> 4)*256 + ((pl1 >> 2) & 3)*64 + (pl1 & 3)*16 + m;

  stage_w(WBe, j0, tid, wlds);
  float bn_e[4], bn_d[4];
#pragma unroll
  for (int d = 0; d < 4; ++d) {
    bn_e[d] = ldf(ebhh, 2*HH + j0 + jb + d, f);
    bn_d[d] = ldf(dbhh, 2*HH + j0 + jb + d, f);
  }
  const int len_e = elen[m], len_d = dlen[m];
  float hreg[4] = {0.f, 0.f, 0.f, 0.f};
  // prefetch gi for s=0 (rows are (t,b)-interleaved: (t*BB+m))
  const float* g0p = gi_e + (size_t)m*G3;
  float4 gr = *(const float4*)(g0p + j0 + jb);
  float4 gz = *(const float4*)(g0p + HH + j0 + jb);
  float4 gn = *(const float4*)(g0p + 2*HH + j0 + jb);
  __syncthreads();   // weights staged

  for (int s = 0; s < TE + TD; ++s) {
    if (s == TE) {   // encoder->decoder: restage weights (prev step's final
                     // sync ordered all wlds MFMA reads)
      stage_w(WBd, j0, tid, wlds);
      __syncthreads();
    }
    const bool enc = s < TE;
    const int t = enc ? s : s - TE;
    // ---- poll: wave w reads source block w's 8 tagged qwords -------------
    const u64_t* hbR = hq + (size_t)(s & 1)*QW_PER_BUF + wave*512 + quad*64 + mrow;
    u64_t qv[8];
    const uint_t target = (uint_t)s;
    int guard = 0;
    for (;;) {
      bool ok = true;
#pragma unroll
      for (int ks = 0; ks < 2; ++ks)
#pragma unroll
        for (int e = 0; e < 4; ++e) {
          qv[ks*4 + e] = __hip_atomic_load(hbR + ks*256 + e*16,
                                           __ATOMIC_RELAXED, __HIP_MEMORY_SCOPE_AGENT);
          ok = ok && ((uint_t)qv[ks*4 + e] == target);
        }
      if (__all(ok) || ++guard > 30000) break;   // bounded (r3 lesson)
    }
    // ---- MFMA: 12 tiles (3 gates x 4 col-tiles), wave's K-slice ----------
    f32x4 acc[3][4];
#pragma unroll
    for (int ga = 0; ga < 3; ++ga)
#pragma unroll
      for (int jt = 0; jt < 4; ++jt) acc[ga][jt] = (f32x4){0.f,0.f,0.f,0.f};
#pragma unroll
    for (int ks = 0; ks < 2; ++ks) {
      union { uint_t u[4]; short8 s8; } av;
#pragma unroll
      for (int e = 0; e < 4; ++e) av.u[e] = (uint_t)(qv[ks*4 + e] >> 32);
      const ushort_t* wb = wlds + mrow*HSBF + wave*64 + ks*32 + quad*8;
#pragma unroll
      for (int ga = 0; ga < 3; ++ga)
#pragma unroll
        for (int jt = 0; jt < 4; ++jt) {
          short8 bv = *(const short8*)(wb + (ga*64 + jt*16)*HSBF);
          acc[ga][jt] = __builtin_amdgcn_mfma_f32_16x16x32_bf16(av.s8, bv, acc[ga][jt], 0, 0, 0);
        }
    }
    // ---- partial store: C-frag row=quad*4+r (batch), col=mrow (dim) ------
#pragma unroll
    for (int ga = 0; ga < 3; ++ga)
#pragma unroll
      for (int jt = 0; jt < 4; ++jt)
#pragma unroll
        for (int r = 0; r < 4; ++r)
          part[wave][ga*4 + jt][quad*4 + r][mrow] = acc[ga][jt][r];
    __syncthreads();   // partials visible
    // ---- reduce K-partials + elementwise (thread owns batch m, dims jb..) -
    const int ttj = g >> 2, cb = (g & 3)*4;
    const int len = enc ? len_e : len_d;
    const bool valid = t < len;
    float h4[4];
#pragma unroll
    for (int d = 0; d < 4; ++d) {
      float ar = 0.f, az = 0.f, an = 0.f;
#pragma unroll
      for (int w = 0; w < 4; ++w) {
        ar += part[w][ttj    ][m][cb + d];
        az += part[w][4 + ttj][m][cb + d];
        an += part[w][8 + ttj][m][cb + d];
      }
      float rr = fsig(gr[d] + ar);                 // bih+bhh pre-folded in gi
      float zz = fsig(gz[d] + az);
      float nn = ftanh(gn[d] + rr*(an + (enc ? bn_e[d] : bn_d[d])));
      float hc = (1.f - zz)*nn + zz*hreg[d];
      h4[d] = valid ? hc : 0.f;
      hreg[d] = valid ? hc : hreg[d];
    }
    float4 ov4 = {h4[0], h4[1], h4[2], h4[3]};
    if (enc) *(float4*)(eout + ((size_t)(m*TE + t))*HH + j0 + jb) = ov4;
    else     *(float4*)(dout + ((size_t)(m*TD + t))*HH + j0 + jb) = ov4;
    // ---- publish 2 tagged h qwords, fire-and-forget ----------------------
    uint_t q0 = (uint_t)f2b(hreg[0]) | ((uint_t)f2b(hreg[1]) << 16);
    uint_t q1 = (uint_t)f2b(hreg[2]) | ((uint_t)f2b(hreg[3]) << 16);
    u64_t* hbW = hq + (size_t)((s + 1) & 1)*QW_PER_BUF;
    __hip_atomic_store(hbW + widx0, ((u64_t)q0 << 32) | (u64_t)(uint_t)(s + 1),
                       __ATOMIC_RELAXED, __HIP_MEMORY_SCOPE_AGENT);
    __hip_atomic_store(hbW + widx1, ((u64_t)q1 << 32) | (u64_t)(uint_t)(s + 1),
                       __ATOMIC_RELAXED, __HIP_MEMORY_SCOPE_AGENT);
    // ---- prefetch next step's gi (overlaps next poll) --------------------
    int s2 = s + 1;
    if (s2 < TE + TD) {
      const float* g2 = (s2 < TE) ? (gi_e + (size_t)(s2*BB + m)*G3)
                                  : (gi_d + (size_t)((s2 - TE)*BB + m)*G3);
      gr = *(const float4*)(g2 + j0 + jb);
      gz = *(const float4*)(g2 + HH + j0 + jb);
      gn = *(const float4*)(g2 + 2*HH + j0 + jb);
    }
    __syncthreads();   // part reads done; next step may overwrite part
  }
}

// ---------------------------------------------------------------------------
// Attention + dense, one block per (b, td). (unchanged from round 8)
// ---------------------------------------------------------------------------
__global__ __launch_bounds__(256) void attn_kernel(
    const float* eprj, const float* dprj, const float* eout, const float* dout,
    const void* Wb, const void* av, const void* avb,
    const ushort_t* DWT, const void* db, const uint_t* flagp,
    const int* elen, const int* dlen, ushort_t* dense_bf) {
  int bd = blockIdx.x;
  int b = bd / TD, td = bd % TD;
  int tid = threadIdx.x;
  int wave = tid >> 6, lane = tid & 63;
  uint_t f = *flagp;
  __shared__ float dp[HH], dsrow[HH], vv[HH], att[TE];
  int el = elen[b];
  bool dok = td < dlen[b];   // uniform per block
  size_t drow = (size_t)bd * HH;
  dp[tid] = dprj[drow + tid] + ldf(Wb, tid, f);
  dsrow[tid] = dout[drow + tid];
  vv[tid] = ldf(av, tid, f);
  if (tid < TE) att[tid] = 0.f;    // weights default 0 (te >= el / invalid td)
  __syncthreads();
  float ctx = 0.f;
  if (dok) {
    float vb0 = ldf(avb, 0, f);
    // ---- energies for te < el, wave-strided ------------------------------
    int nteb = (el + 3) >> 2;
    for (int teb = 0; teb < nteb; ++teb) {
      int te = teb*4 + wave;          // wave-uniform
      if (te < el) {
        const float* ep = eprj + (size_t)(b*TE + te)*HH;
        float s = 0.f;
#pragma unroll
        for (int i = 0; i < 4; ++i) {
          int hh = lane + 64*i;
          s += ftanh(ep[hh] + dp[hh]) * vv[hh];
        }
#pragma unroll
        for (int off = 32; off > 0; off >>= 1) s += __shfl_xor(s, off);
        if (lane == 0) att[te] = s + vb0;
      }
    }
    __syncthreads();
    // ---- softmax over valid prefix --------------------------------------
    float mx = -1e30f;
    for (int te = 0; te < el; ++te) mx = fmaxf(mx, att[te]);
    __syncthreads();                 // all reads of raw energies done
    if (tid < el) att[tid] = __expf(att[tid] - mx);
    __syncthreads();
    float ssum = 0.f;
    for (int te = 0; te < el; ++te) ssum += att[te];
    float inv = (ssum > 0.f) ? 1.f/ssum : 0.f;
    // ---- context: branchless, 4 accumulators -----------------------------
    const float* ebase = eout + (size_t)(b*TE)*HH + tid;
    float c0 = 0.f, c1 = 0.f, c2 = 0.f, c3 = 0.f;
    int te = 0;
    for (; te + 4 <= el; te += 4) {
      c0 += att[te    ] * ebase[(size_t)(te    )*HH];
      c1 += att[te + 1] * ebase[(size_t)(te + 1)*HH];
      c2 += att[te + 2] * ebase[(size_t)(te + 2)*HH];
      c3 += att[te + 3] * ebase[(size_t)(te + 3)*HH];
    }
    for (; te < el; ++te) c0 += att[te] * ebase[(size_t)te*HH];
    ctx = (c0 + c1 + c2 + c3) * inv;
  }
  __syncthreads();                   // att/dp reads done before dp reuse
  dp[tid] = ctx;                     // reuse dp as context
  __syncthreads();
  // ---- dense: acc = b + dsrow@W1col + ctx@W2col, 4 accumulators ----------
  const ushort_t* w0 = DWT + tid;
  float a0 = ldf(db, tid, f), a1 = 0.f, a2 = 0.f, a3 = 0.f;
#pragma unroll 8
  for (int k = 0; k < HH; k += 4) {
    a0 = fmaf(b2f(w0[(size_t)(k    )*HH]), dsrow[k    ], a0);
    a1 = fmaf(b2f(w0[(size_t)(k + 1)*HH]), dsrow[k + 1], a1);
    a2 = fmaf(b2f(w0[(size_t)(k + 2)*HH]), dsrow[k + 2], a2);
    a3 = fmaf(b2f(w0[(size_t)(k + 3)*HH]), dsrow[k + 3], a3);
  }
#pragma unroll 8
  for (int k = 0; k < HH; k += 4) {
    a0 = fmaf(b2f(w0[(size_t)(HH + k    )*HH]), dp[k    ], a0);
    a1 = fmaf(b2f(w0[(size_t)(HH + k + 1)*HH]), dp[k + 1], a1);
    a2 = fmaf(b2f(w0[(size_t)(HH + k + 2)*HH]), dp[k + 2], a2);
    a3 = fmaf(b2f(w0[(size_t)(HH + k + 3)*HH]), dp[k + 3], a3);
  }
  dense_bf[drow + tid] = f2b(ftanh(a0 + a1 + a2 + a3));
}

// ---------------------------------------------------------------------------
extern "C" void kernel_launch(void* const* d_in, const int* in_sizes, int n_in,
                              void* d_out, int out_size, void* d_ws, size_t ws_size,
                              hipStream_t stream) {
  const int* enc_in   = (const int*)d_in[0];
  const int* enc_len  = (const int*)d_in[1];
  const int* dec_in   = (const int*)d_in[2];
  const int* dec_len  = (const int*)d_in[3];
  const void* emb    = d_in[4];
  const void* eWih   = d_in[5];
  const void* eWhh   = d_in[6];
  const void* ebih   = d_in[7];
  const void* ebhh   = d_in[8];
  const void* dWih   = d_in[9];
  const void* dWhh   = d_in[10];
  const void* dbih   = d_in[11];
  const void* dbhh   = d_in[12];
  const void* attnW  = d_in[13];
  const void* attnWb = d_in[14];
  const void* attnv  = d_in[15];
  const void* attnvb = d_in[16];
  const void* denseW = d_in[17];
  const void* denseb = d_in[18];
  const void* outW   = d_in[19];
  const void* outb   = d_in[20];
  float* out = (float*)d_out;   // reference output is fp32

  float* ws = (float*)d_ws;
  size_t o = 0;
  uint_t* flag = (uint_t*)(ws + o);   o += 4;
  u64_t* hq = (u64_t*)(ws + o);       o += 4*QW_PER_BUF;  // 2 bufs x 2048 qwords
  ushort_t* WBe = (ushort_t*)(ws + o); o += G3*KK/2;
  ushort_t* WBd = (ushort_t*)(ws + o); o += G3*KK/2;
  ushort_t* DWT = (ushort_t*)(ws + o); o += 512*HH/2;
  float* cbe = ws + o;                o += G3;
  float* cbd = ws + o;                o += G3;
  float* obf = ws + o;                o += OUTV;
  float* gi_e = ws + o;               o += (size_t)MROWS_E*G3;   // (t,b)-interleaved
  float* gi_d = ws + o;               o += (size_t)MROWS_D*G3;   // (t,b)-interleaved
  float* eout = ws + o;               o += (size_t)MROWS_E*HH;
  float* dout = ws + o;               o += (size_t)MROWS_D*HH;
  float* eprj = ws + o;               o += (size_t)MROWS_E*HH;
  float* dprj = ws + o;               o += (size_t)MROWS_D*HH;
  ushort_t* dense_bf = (ushort_t*)(ws + o); o += (size_t)MROWS_D*HH/2;

  detect_kernel<<<1, 256, 0, stream>>>(emb, flag);
  prep_kernel<<<384, 256, 0, stream>>>(eWhh, dWhh, denseW, ebih, ebhh, dbih, dbhh,
                                       outb, flag, WBe, WBd, DWT, cbe, cbd, obf, hq);
  // gi = emb[tokens] @ Wih.T + (bih + bhh[r,z]), rows (t,b)-interleaved
  gemm_kernel<<<dim3(12,8), 256, 0, stream>>>(nullptr, enc_in, emb, eWih, 256, 0,
                                              cbe, flag, gi_e, nullptr, G3, MROWS_E, 7, 0);
  gemm_kernel<<<dim3(12,4), 256, 0, stream>>>(nullptr, dec_in, emb, dWih, 256, 0,
                                              cbd, flag, gi_d, nullptr, G3, MROWS_D, 6, 0);
  gru_kernel<<<NBLK, 256, 0, stream>>>(gi_e, gi_d, WBe, WBd, ebhh, dbhh, flag,
                                       enc_len, dec_len, eout, dout, hq);
  // enc_proj = enc_out @ W1.T ; dec_proj = dec_out @ W2.T  (attn_W col split)
  gemm_kernel<<<dim3(4,16), 256, 0, stream>>>((const ushort_t*)eout, nullptr, nullptr,
                                              attnW, 512, 0, nullptr, flag, eprj,
                                              nullptr, HH, MROWS_E, 0, 1);
  gemm_kernel<<<dim3(4,8), 256, 0, stream>>>((const ushort_t*)dout, nullptr, nullptr,
                                             attnW, 512, 256, nullptr, flag, dprj,
                                             nullptr, HH, MROWS_D, 0, 1);
  attn_kernel<<<MROWS_D, 256, 0, stream>>>(eprj, dprj, eout, dout, attnWb, attnv, attnvb,
                                           DWT, denseb, flag, enc_len, dec_len, dense_bf);
  // logits = dense @ out_W.T + out_b  (fp32 out)
  gemm_kernel<<<dim3(500,4), 256, 0, stream>>>(dense_bf, nullptr, nullptr, outW, 256, 0,
                                               obf, flag, out, nullptr, OUTV, MROWS_D, 0, 0);
}

// Round 10
// 786.429 us; speedup vs baseline: 1.1887x; 1.1887x over previous
//
#include <hip/hip_runtime.h>
#include <hip/hip_bf16.h>

typedef unsigned short ushort_t;
typedef unsigned int uint_t;
typedef unsigned long long u64_t;

#define BB 16
#define TE 128
#define TD 64
#define HH 256
#define G3 768
#define KK 256
#define OUTV 32000
#define MROWS_E (BB*TE)   // 2048
#define MROWS_D (BB*TD)   // 1024
#define NBLK 16           // GRU blocks (CUs); each owns JD h-dims
#define JD 16
#define QW_PER_BUF 2048   // {2xbf16, tag} qwords per h snapshot

typedef __attribute__((ext_vector_type(8))) short short8;
typedef __attribute__((ext_vector_type(4))) float f32x4;

__device__ __forceinline__ float b2f(ushort_t u) {
  union { uint_t i; float f; } v; v.i = ((uint_t)u) << 16; return v.f;
}
__device__ __forceinline__ ushort_t f2b(float f) {
  union { float f; uint_t i; } v; v.f = f;
  uint_t x = v.i;
  return (ushort_t)((x + 0x7fffu + ((x >> 16) & 1u)) >> 16);
}
// dtype-adaptive scalar load of a "float" input: f32f!=0 -> fp32 buffer, else bf16
__device__ __forceinline__ float ldf(const void* p, size_t i, uint_t f32f) {
  return f32f ? ((const float*)p)[i] : b2f(((const ushort_t*)p)[i]);
}
// fast, saturating sigmoid/tanh (inputs bounded; formulas robust at +-inf)
__device__ __forceinline__ float fsig(float x) { return 1.f/(1.f + __expf(-x)); }
__device__ __forceinline__ float ftanh(float x) { return 1.f - 2.f/(__expf(2.f*x) + 1.f); }

// ---------------------------------------------------------------------------
// dtype detector (fp32 on this harness; kept for safety).
// ---------------------------------------------------------------------------
__global__ __launch_bounds__(256) void detect_kernel(const void* emb, uint_t* flag) {
  int tid = threadIdx.x;
  uint_t w = ((const uint_t*)emb)[tid];
  uint_t e = (w >> 7) & 0xFFu;
  bool pass = (e >= 100u && e <= 127u);
  unsigned long long m = __ballot(pass);
  __shared__ int cnt[4];
  if ((tid & 63) == 0) cnt[tid >> 6] = __popcll(m);
  __syncthreads();
  if (tid == 0) {
    int c = cnt[0] + cnt[1] + cnt[2] + cnt[3];
    *flag = (c >= 128) ? 0u : 1u;
  }
}

// ---------------------------------------------------------------------------
// prep: Whh -> bf16 [768][256]; dense_W -> bf16 transpose; out_W -> bf16
// (ONE conversion here removes 4x-redundant fp32 B reads + in-loop f2b from
// the 2000-block out-GEMM); combined gi biases (bih + bhh folded for r,z);
// out bias -> fp32; zero tagged h-exchange buffer.
// ---------------------------------------------------------------------------
__global__ __launch_bounds__(256) void prep_kernel(
    const void* eWhh, const void* dWhh, const void* denseW, const void* outW,
    const void* ebih, const void* ebhh, const void* dbih, const void* dbhh,
    const void* outb, const uint_t* flagp,
    ushort_t* WBe, ushort_t* WBd, ushort_t* DWT, ushort_t* obW,
    float* cbe, float* cbd, float* obf, u64_t* hq) {
  uint_t f = *flagp;
  int tid = blockIdx.x * blockDim.x + threadIdx.x;
  int nth = gridDim.x * blockDim.x;
  for (int i = tid; i < G3*KK; i += nth) {
    WBe[i] = f2b(ldf(eWhh, i, f));
    WBd[i] = f2b(ldf(dWhh, i, f));
  }
  for (int i = tid; i < 512*HH; i += nth) {
    int k = i / HH, c = i % HH;
    DWT[i] = f2b(ldf(denseW, (size_t)c*512 + k, f));
  }
  for (size_t i = tid; i < (size_t)OUTV*HH; i += nth) obW[i] = f2b(ldf(outW, i, f));
  for (int i = tid; i < G3; i += nth) {
    float be = ldf(ebih, i, f), bd = ldf(dbih, i, f);
    if (i < 2*HH) { be += ldf(ebhh, i, f); bd += ldf(dbhh, i, f); }
    cbe[i] = be; cbd[i] = bd;
  }
  for (int i = tid; i < OUTV; i += nth) obf[i] = ldf(outb, i, f);
  for (int i = tid; i < 2*QW_PER_BUF; i += nth) hq[i] = 0ull;  // tag0 + h=0
}

// ---------------------------------------------------------------------------
// Generic MFMA GEMM: C[m][n] = sum_k A[m][k]*B[n][k] (+bias[n]), K=256 fixed.
// tshift!=0: output rows remapped m=(b*T+t) -> t*BB+b with T=1<<tshift.
// a_f32!=0: ws A operand is fp32 (converted to bf16 during staging).
// b_bf16!=0: Bw is a prep-produced bf16 buffer regardless of input dtype.
// bias (if non-null) is always fp32 (prep-produced).
// ---------------------------------------------------------------------------
#define LDT 264

__global__ __launch_bounds__(256) void gemm_kernel(
    const ushort_t* A, const int* tokens, const void* emb,
    const void* Bw, int ldb, int b_off,
    const float* bias, const uint_t* flagp,
    float* Cf, ushort_t* Cb, int ldc, int M, int tshift, int a_f32, int b_bf16) {
  __shared__ __align__(16) ushort_t Bs[64*LDT];
  __shared__ __align__(16) ushort_t As[32*LDT];
  uint_t f = *flagp;
  int tid = threadIdx.x;
  int wave = tid >> 6, lane = tid & 63;
  int n0 = blockIdx.x * 64;
#pragma unroll
  for (int it = 0; it < 8; ++it) {
    int idx = it*256 + tid;
    int row = idx >> 5, col = (idx & 31) << 3;
    size_t e = (size_t)(n0 + row)*ldb + col + b_off;
    uint4 v;
    if (f && !b_bf16) {
      const float4* s = (const float4*)((const float*)Bw + e);
      float4 x = s[0], y = s[1];
      v.x = (uint_t)f2b(x.x) | ((uint_t)f2b(x.y) << 16);
      v.y = (uint_t)f2b(x.z) | ((uint_t)f2b(x.w) << 16);
      v.z = (uint_t)f2b(y.x) | ((uint_t)f2b(y.y) << 16);
      v.w = (uint_t)f2b(y.z) | ((uint_t)f2b(y.w) << 16);
    } else {
      v = *(const uint4*)((const ushort_t*)Bw + e);
    }
    *(uint4*)(Bs + row*LDT + col) = v;
  }
  int arow_i = lane & 15;
  float bias_v = 0.f;
  if (bias) bias_v = bias[n0 + wave*16 + arow_i];
  int koff = (lane >> 4) << 3;
  for (int m0 = blockIdx.y*32; m0 < M; m0 += gridDim.y*32) {
    __syncthreads();   // Bs ready / previous chunk compute done
#pragma unroll
    for (int it = 0; it < 4; ++it) {
      int idx = it*256 + tid;
      int row = idx >> 5, col = (idx & 31) << 3;
      uint4 v;
      if (tokens) {
        size_t e = (size_t)tokens[m0 + row]*KK + col;
        if (f) {
          const float4* s = (const float4*)((const float*)emb + e);
          float4 x = s[0], y = s[1];
          v.x = (uint_t)f2b(x.x) | ((uint_t)f2b(x.y) << 16);
          v.y = (uint_t)f2b(x.z) | ((uint_t)f2b(x.w) << 16);
          v.z = (uint_t)f2b(y.x) | ((uint_t)f2b(y.y) << 16);
          v.w = (uint_t)f2b(y.z) | ((uint_t)f2b(y.w) << 16);
        } else {
          v = *(const uint4*)((const ushort_t*)emb + e);
        }
      } else if (a_f32) {
        const float4* s = (const float4*)((const float*)A + (size_t)(m0 + row)*KK + col);
        float4 x = s[0], y = s[1];
        v.x = (uint_t)f2b(x.x) | ((uint_t)f2b(x.y) << 16);
        v.y = (uint_t)f2b(x.z) | ((uint_t)f2b(x.w) << 16);
        v.z = (uint_t)f2b(y.x) | ((uint_t)f2b(y.y) << 16);
        v.w = (uint_t)f2b(y.z) | ((uint_t)f2b(y.w) << 16);
      } else {
        v = *(const uint4*)(A + (size_t)(m0 + row)*KK + col);  // ws bf16
      }
      *(uint4*)(As + row*LDT + col) = v;
    }
    __syncthreads();
#pragma unroll
    for (int msub = 0; msub < 2; ++msub) {
      f32x4 acc = {0.f,0.f,0.f,0.f};
      const ushort_t* ap = As + (msub*16 + arow_i)*LDT + koff;
      const ushort_t* bp = Bs + (wave*16 + arow_i)*LDT + koff;
#pragma unroll
      for (int ks = 0; ks < 8; ++ks) {
        short8 af = *(const short8*)(ap + ks*32);
        short8 bf = *(const short8*)(bp + ks*32);
        acc = __builtin_amdgcn_mfma_f32_16x16x32_bf16(af, bf, acc, 0, 0, 0);
      }
      int mbase = m0 + msub*16 + (lane >> 4)*4;
      int ncol = n0 + wave*16 + arow_i;
#pragma unroll
      for (int r = 0; r < 4; ++r) {
        float val = acc[r] + bias_v;
        int mr = mbase + r;
        int orow = tshift ? (((mr & ((1 << tshift) - 1)) << 4) + (mr >> tshift)) : mr;
        if (Cf) Cf[(size_t)orow*ldc + ncol] = val;
        else    Cb[(size_t)orow*ldc + ncol] = f2b(val);
      }
    }
  }
}

// ---------------------------------------------------------------------------
// Multi-CU MFMA GRU (REVERTED to the round-6/8 16-block version -- 330 us.
// Round-9's 4x64 repartition REGRESSED to 521 us: fewer participants did not
// shrink the exchange RTT (already coalesced) but 4x'd per-step serial
// compute per CU. 16 blocks x 16 dims is the local optimum for this design.)
// ---------------------------------------------------------------------------
#define HSBF 264            // LDS row stride (bf16 elems): <=2-way banks on b128

__device__ __forceinline__ void stage_w(const ushort_t* WB, int j0, int tid,
                                        ushort_t* wlds) {
#pragma unroll
  for (int it = 0; it < 6; ++it) {
    int idx = it*256 + tid;
    int row = idx >> 5, col = (idx & 31) << 3;   // row 0..47, col 0..255 step 8
    const ushort_t* src = WB + ((size_t)((row >> 4)*HH + j0 + (row & 15)))*KK + col;
    *(uint4*)(wlds + row*HSBF + col) = *(const uint4*)src;
  }
}

__global__ __launch_bounds__(256) void gru_kernel(
    const float* gi_e, const float* gi_d, const ushort_t* WBe, const ushort_t* WBd,
    const void* ebhh, const void* dbhh, const uint_t* flagp,
    const int* elen, const int* dlen, float* eout, float* dout, u64_t* hq) {
  uint_t f = *flagp;
  __shared__ __align__(16) ushort_t wlds[48*HSBF];        // 24.75 KB
  __shared__ __align__(16) float part[2][4][3][16][17];   // 25.5 KB parity-dbuf
  const int tid = threadIdx.x;
  const int wave = tid >> 6, lane = tid & 63;
  const int mrow = lane & 15, quad = lane >> 4;           // MFMA fragment coords
  const int j0 = blockIdx.x * JD;
  const int m = tid >> 4, n = tid & 15;                   // elementwise coords
  const int j = j0 + n;
  // permuted publish index for this thread's (even) pair base j & ~1:
  const int je = j & ~1;
  const int widx = ((je >> 6) << 9) + (((je >> 5) & 1) << 8)
                 + (((je >> 1) & 3) << 6) + (((je >> 3) & 3) << 4) + m;

  stage_w(WBe, j0, tid, wlds);
  const float bn_e = ldf(ebhh, 2*HH + j, f);
  const float bn_d = ldf(dbhh, 2*HH + j, f);
  const int len_e = elen[m], len_d = dlen[m];
  float hreg = 0.f;
  // prefetch gi for s=0 (rows are (t,b)-interleaved: (t*BB+m))
  float grv = gi_e[(size_t)m*G3 + j];
  float gzv = gi_e[(size_t)m*G3 + HH + j];
  float gnv = gi_e[(size_t)m*G3 + 2*HH + j];
  __syncthreads();   // weights staged

  for (int s = 0; s < TE + TD; ++s) {
    if (s == TE) {   // encoder->decoder: restage weights. All threads passed
                     // step TE-1's mid-step sync (after their last wlds MFMA
                     // reads); EW phase never touches wlds. Sync after.
      stage_w(WBd, j0, tid, wlds);
      __syncthreads();
    }
    const bool enc = s < TE;
    const int t = enc ? s : s - TE;
    // ---- poll own wave's 8 tagged qwords (coalesced layout) --------------
    const u64_t* hbR = hq + (size_t)(s & 1)*QW_PER_BUF + wave*512 + lane;
    u64_t qv[8];
    const uint_t target = (uint_t)s;
    int guard = 0;
    for (;;) {
      bool ok = true;
#pragma unroll
      for (int ks = 0; ks < 2; ++ks)
#pragma unroll
        for (int i = 0; i < 4; ++i) {
          qv[ks*4 + i] = __hip_atomic_load(hbR + ks*256 + i*64,
                                           __ATOMIC_RELAXED, __HIP_MEMORY_SCOPE_AGENT);
          ok = ok && ((uint_t)qv[ks*4 + i] == target);
        }
      if (__all(ok) || ++guard > 30000) break;   // bounded (r3 lesson)
    }
    // ---- MFMA: 3 gate tiles, wave's K-slice = [64*wave, 64*wave+64) ------
    f32x4 ar = {0.f,0.f,0.f,0.f}, az = {0.f,0.f,0.f,0.f}, an = {0.f,0.f,0.f,0.f};
#pragma unroll
    for (int ks = 0; ks < 2; ++ks) {
      union { uint_t u[4]; short8 s8; } av;
#pragma unroll
      for (int i = 0; i < 4; ++i) av.u[i] = (uint_t)(qv[ks*4 + i] >> 32);
      const ushort_t* wp = wlds + mrow*HSBF + wave*64 + ks*32 + quad*8;
      short8 b0 = *(const short8*)(wp);
      short8 b1 = *(const short8*)(wp + 16*HSBF);
      short8 b2 = *(const short8*)(wp + 32*HSBF);
      ar = __builtin_amdgcn_mfma_f32_16x16x32_bf16(av.s8, b0, ar, 0, 0, 0);
      az = __builtin_amdgcn_mfma_f32_16x16x32_bf16(av.s8, b1, az, 0, 0, 0);
      an = __builtin_amdgcn_mfma_f32_16x16x32_bf16(av.s8, b2, an, 0, 0, 0);
    }
    // ---- partial store: C-frag row=quad*4+r (m), col=mrow (n) -------------
    const int p = s & 1;
#pragma unroll
    for (int r = 0; r < 4; ++r) {
      part[p][wave][0][quad*4 + r][mrow] = ar[r];
      part[p][wave][1][quad*4 + r][mrow] = az[r];
      part[p][wave][2][quad*4 + r][mrow] = an[r];
    }
    __syncthreads();   // the ONLY per-step block barrier
    // ---- reduce K-partials + elementwise (thread owns (m, j)) ------------
    float accr = 0.f, accz = 0.f, accn = 0.f;
#pragma unroll
    for (int w = 0; w < 4; ++w) {
      accr += part[p][w][0][m][n];
      accz += part[p][w][1][m][n];
      accn += part[p][w][2][m][n];
    }
    float rr = fsig(grv + accr);                    // bih+bhh pre-folded in gi
    float zz = fsig(gzv + accz);
    float nn = ftanh(gnv + rr*(accn + (enc ? bn_e : bn_d)));
    float hc = (1.f - zz)*nn + zz*hreg;
    bool valid = t < (enc ? len_e : len_d);
    float ov = valid ? hc : 0.f;
    hreg = valid ? hc : hreg;
    if (enc) eout[((size_t)(m*TE + t))*HH + j] = ov;
    else     dout[((size_t)(m*TD + t))*HH + j] = ov;
    // ---- publish tagged h qword (even n lanes), fire-and-forget ----------
    uint_t h16 = (uint_t)f2b(hreg);
    uint_t up = (uint_t)__shfl_down((int)h16, 1);
    if (!(n & 1)) {
      u64_t q = ((u64_t)(h16 | (up << 16)) << 32) | (u64_t)(uint_t)(s + 1);
      __hip_atomic_store(hq + (size_t)((s + 1) & 1)*QW_PER_BUF + widx,
                         q, __ATOMIC_RELAXED, __HIP_MEMORY_SCOPE_AGENT);
    }
    // ---- prefetch next step's gi (overlaps next poll) --------------------
    int s2 = s + 1;
    if (s2 < TE + TD) {
      const float* g2 = (s2 < TE) ? (gi_e + (size_t)(s2*BB + m)*G3)
                                  : (gi_d + (size_t)((s2 - TE)*BB + m)*G3);
      grv = g2[j]; gzv = g2[HH + j]; gnv = g2[2*HH + j];
    }
  }
}

// ---------------------------------------------------------------------------
// Attention + dense, one block per (b, td). (unchanged from round 8)
// ---------------------------------------------------------------------------
__global__ __launch_bounds__(256) void attn_kernel(
    const float* eprj, const float* dprj, const float* eout, const float* dout,
    const void* Wb, const void* av, const void* avb,
    const ushort_t* DWT, const void* db, const uint_t* flagp,
    const int* elen, const int* dlen, ushort_t* dense_bf) {
  int bd = blockIdx.x;
  int b = bd / TD, td = bd % TD;
  int tid = threadIdx.x;
  int wave = tid >> 6, lane = tid & 63;
  uint_t f = *flagp;
  __shared__ float dp[HH], dsrow[HH], vv[HH], att[TE];
  int el = elen[b];
  bool dok = td < dlen[b];   // uniform per block
  size_t drow = (size_t)bd * HH;
  dp[tid] = dprj[drow + tid] + ldf(Wb, tid, f);
  dsrow[tid] = dout[drow + tid];
  vv[tid] = ldf(av, tid, f);
  if (tid < TE) att[tid] = 0.f;    // weights default 0 (te >= el / invalid td)
  __syncthreads();
  float ctx = 0.f;
  if (dok) {
    float vb0 = ldf(avb, 0, f);
    // ---- energies for te < el, wave-strided ------------------------------
    int nteb = (el + 3) >> 2;
    for (int teb = 0; teb < nteb; ++teb) {
      int te = teb*4 + wave;          // wave-uniform
      if (te < el) {
        const float* ep = eprj + (size_t)(b*TE + te)*HH;
        float s = 0.f;
#pragma unroll
        for (int i = 0; i < 4; ++i) {
          int hh = lane + 64*i;
          s += ftanh(ep[hh] + dp[hh]) * vv[hh];
        }
#pragma unroll
        for (int off = 32; off > 0; off >>= 1) s += __shfl_xor(s, off);
        if (lane == 0) att[te] = s + vb0;
      }
    }
    __syncthreads();
    // ---- softmax over valid prefix --------------------------------------
    float mx = -1e30f;
    for (int te = 0; te < el; ++te) mx = fmaxf(mx, att[te]);
    __syncthreads();                 // all reads of raw energies done
    if (tid < el) att[tid] = __expf(att[tid] - mx);
    __syncthreads();
    float ssum = 0.f;
    for (int te = 0; te < el; ++te) ssum += att[te];
    float inv = (ssum > 0.f) ? 1.f/ssum : 0.f;
    // ---- context: branchless, 4 accumulators -----------------------------
    const float* ebase = eout + (size_t)(b*TE)*HH + tid;
    float c0 = 0.f, c1 = 0.f, c2 = 0.f, c3 = 0.f;
    int te = 0;
    for (; te + 4 <= el; te += 4) {
      c0 += att[te    ] * ebase[(size_t)(te    )*HH];
      c1 += att[te + 1] * ebase[(size_t)(te + 1)*HH];
      c2 += att[te + 2] * ebase[(size_t)(te + 2)*HH];
      c3 += att[te + 3] * ebase[(size_t)(te + 3)*HH];
    }
    for (; te < el; ++te) c0 += att[te] * ebase[(size_t)te*HH];
    ctx = (c0 + c1 + c2 + c3) * inv;
  }
  __syncthreads();                   // att/dp reads done before dp reuse
  dp[tid] = ctx;                     // reuse dp as context
  __syncthreads();
  // ---- dense: acc = b + dsrow@W1col + ctx@W2col, 4 accumulators ----------
  const ushort_t* w0 = DWT + tid;
  float a0 = ldf(db, tid, f), a1 = 0.f, a2 = 0.f, a3 = 0.f;
#pragma unroll 8
  for (int k = 0; k < HH; k += 4) {
    a0 = fmaf(b2f(w0[(size_t)(k    )*HH]), dsrow[k    ], a0);
    a1 = fmaf(b2f(w0[(size_t)(k + 1)*HH]), dsrow[k + 1], a1);
    a2 = fmaf(b2f(w0[(size_t)(k + 2)*HH]), dsrow[k + 2], a2);
    a3 = fmaf(b2f(w0[(size_t)(k + 3)*HH]), dsrow[k + 3], a3);
  }
#pragma unroll 8
  for (int k = 0; k < HH; k += 4) {
    a0 = fmaf(b2f(w0[(size_t)(HH + k    )*HH]), dp[k    ], a0);
    a1 = fmaf(b2f(w0[(size_t)(HH + k + 1)*HH]), dp[k + 1], a1);
    a2 = fmaf(b2f(w0[(size_t)(HH + k + 2)*HH]), dp[k + 2], a2);
    a3 = fmaf(b2f(w0[(size_t)(HH + k + 3)*HH]), dp[k + 3], a3);
  }
  dense_bf[drow + tid] = f2b(ftanh(a0 + a1 + a2 + a3));
}

// ---------------------------------------------------------------------------
extern "C" void kernel_launch(void* const* d_in, const int* in_sizes, int n_in,
                              void* d_out, int out_size, void* d_ws, size_t ws_size,
                              hipStream_t stream) {
  const int* enc_in   = (const int*)d_in[0];
  const int* enc_len  = (const int*)d_in[1];
  const int* dec_in   = (const int*)d_in[2];
  const int* dec_len  = (const int*)d_in[3];
  const void* emb    = d_in[4];
  const void* eWih   = d_in[5];
  const void* eWhh   = d_in[6];
  const void* ebih   = d_in[7];
  const void* ebhh   = d_in[8];
  const void* dWih   = d_in[9];
  const void* dWhh   = d_in[10];
  const void* dbih   = d_in[11];
  const void* dbhh   = d_in[12];
  const void* attnW  = d_in[13];
  const void* attnWb = d_in[14];
  const void* attnv  = d_in[15];
  const void* attnvb = d_in[16];
  const void* denseW = d_in[17];
  const void* denseb = d_in[18];
  const void* outW   = d_in[19];
  const void* outb   = d_in[20];
  float* out = (float*)d_out;   // reference output is fp32

  float* ws = (float*)d_ws;
  size_t o = 0;
  uint_t* flag = (uint_t*)(ws + o);   o += 4;
  u64_t* hq = (u64_t*)(ws + o);       o += 4*QW_PER_BUF;  // 2 bufs x 2048 qwords
  ushort_t* WBe = (ushort_t*)(ws + o); o += G3*KK/2;
  ushort_t* WBd = (ushort_t*)(ws + o); o += G3*KK/2;
  ushort_t* DWT = (ushort_t*)(ws + o); o += 512*HH/2;
  ushort_t* obW = (ushort_t*)(ws + o); o += (size_t)OUTV*HH/2;  // bf16 out_W
  float* cbe = ws + o;                o += G3;
  float* cbd = ws + o;                o += G3;
  float* obf = ws + o;                o += OUTV;
  float* gi_e = ws + o;               o += (size_t)MROWS_E*G3;   // (t,b)-interleaved
  float* gi_d = ws + o;               o += (size_t)MROWS_D*G3;   // (t,b)-interleaved
  float* eout = ws + o;               o += (size_t)MROWS_E*HH;
  float* dout = ws + o;               o += (size_t)MROWS_D*HH;
  float* eprj = ws + o;               o += (size_t)MROWS_E*HH;
  float* dprj = ws + o;               o += (size_t)MROWS_D*HH;
  ushort_t* dense_bf = (ushort_t*)(ws + o); o += (size_t)MROWS_D*HH/2;

  detect_kernel<<<1, 256, 0, stream>>>(emb, flag);
  prep_kernel<<<384, 256, 0, stream>>>(eWhh, dWhh, denseW, outW, ebih, ebhh, dbih,
                                       dbhh, outb, flag, WBe, WBd, DWT, obW,
                                       cbe, cbd, obf, hq);
  // gi = emb[tokens] @ Wih.T + (bih + bhh[r,z]), rows (t,b)-interleaved
  gemm_kernel<<<dim3(12,8), 256, 0, stream>>>(nullptr, enc_in, emb, eWih, 256, 0,
                                              cbe, flag, gi_e, nullptr, G3, MROWS_E, 7, 0, 0);
  gemm_kernel<<<dim3(12,4), 256, 0, stream>>>(nullptr, dec_in, emb, dWih, 256, 0,
                                              cbd, flag, gi_d, nullptr, G3, MROWS_D, 6, 0, 0);
  gru_kernel<<<NBLK, 256, 0, stream>>>(gi_e, gi_d, WBe, WBd, ebhh, dbhh, flag,
                                       enc_len, dec_len, eout, dout, hq);
  // enc_proj = enc_out @ W1.T ; dec_proj = dec_out @ W2.T  (attn_W col split)
  gemm_kernel<<<dim3(4,16), 256, 0, stream>>>((const ushort_t*)eout, nullptr, nullptr,
                                              attnW, 512, 0, nullptr, flag, eprj,
                                              nullptr, HH, MROWS_E, 0, 1, 0);
  gemm_kernel<<<dim3(4,8), 256, 0, stream>>>((const ushort_t*)dout, nullptr, nullptr,
                                             attnW, 512, 256, nullptr, flag, dprj,
                                             nullptr, HH, MROWS_D, 0, 1, 0);
  attn_kernel<<<MROWS_D, 256, 0, stream>>>(eprj, dprj, eout, dout, attnWb, attnv, attnvb,
                                           DWT, denseb, flag, enc_len, dec_len, dense_bf);
  // logits = dense @ out_W.T + out_b  (fp32 out; B pre-converted to bf16)
  gemm_kernel<<<dim3(500,4), 256, 0, stream>>>(dense_bf, nullptr, nullptr, obW, 256, 0,
                                               obf, flag, out, nullptr, OUTV, MROWS_D, 0, 0, 1);
}